// Round 1
// baseline (148.166 us; speedup 1.0000x reference)
//
#include <hip/hip_runtime.h>
#include <stdint.h>

// Problem constants (fixed by setup_inputs: B=4, N_obj=8, N_v=2048)
#define NPTS 2048
#define KNN  16
#define AK   64
#define TPB  256
#define PPT  (NPTS / TPB)   // 8 points per thread

// Exact float32 helpers (no FMA contraction -> match numpy/XLA-CPU reference)
__device__ __forceinline__ float sq3(float x, float y, float z) {
    return __fadd_rn(__fadd_rn(__fmul_rn(x, x), __fmul_rn(y, y)), __fmul_rn(z, z));
}

// ---------------------------------------------------------------------------
// Kernel 1: farthest-point sampling, one block per object.
// anchors[obj][0] = 0; anchors[obj][s] = argmax(min_d) with first-index ties,
// min_d updated as min(min_d, ||p - p_anchor||^2), exactly as the lax.scan.
// ---------------------------------------------------------------------------
__global__ __launch_bounds__(TPB) void fps_kernel(const float* __restrict__ pos,
                                                  int* __restrict__ anchors) {
    const int obj = blockIdx.x;
    const float* pts = pos + (size_t)obj * NPTS * 3;
    const int t = threadIdx.x;

    float px[PPT], py[PPT], pz[PPT], mind[PPT];
    const float ax0 = pts[0], ay0 = pts[1], az0 = pts[2];
    #pragma unroll
    for (int i = 0; i < PPT; i++) {
        const int j = t + i * TPB;
        px[i] = pts[j * 3 + 0];
        py[i] = pts[j * 3 + 1];
        pz[i] = pts[j * 3 + 2];
        const float dx = __fsub_rn(px[i], ax0);
        const float dy = __fsub_rn(py[i], ay0);
        const float dz = __fsub_rn(pz[i], az0);
        mind[i] = sq3(dx, dy, dz);
    }

    __shared__ unsigned long long skey[TPB];
    if (t == 0) anchors[obj * AK + 0] = 0;

    for (int s = 1; s < AK; s++) {
        // local argmax over this thread's points; key packs (value, ~index)
        // so max-key == (max value, smallest index on ties). mind >= 0 so the
        // raw float bit pattern is order-monotonic.
        unsigned long long best = 0ull;
        #pragma unroll
        for (int i = 0; i < PPT; i++) {
            const int j = t + i * TPB;
            const unsigned int b = __float_as_uint(mind[i]);
            const unsigned long long key =
                ((unsigned long long)b << 32) | (unsigned int)(~j);
            if (key > best) best = key;
        }
        skey[t] = best;
        __syncthreads();
        for (int off = TPB / 2; off > 0; off >>= 1) {
            if (t < off) {
                if (skey[t + off] > skey[t]) skey[t] = skey[t + off];
            }
            __syncthreads();
        }
        const int idx = (int)(~((unsigned int)skey[0]));
        if (t == 0) anchors[obj * AK + s] = idx;

        const float bx = pts[idx * 3 + 0];
        const float by = pts[idx * 3 + 1];
        const float bz = pts[idx * 3 + 2];
        #pragma unroll
        for (int i = 0; i < PPT; i++) {
            const float dx = __fsub_rn(px[i], bx);
            const float dy = __fsub_rn(py[i], by);
            const float dz = __fsub_rn(pz[i], bz);
            mind[i] = fminf(mind[i], sq3(dx, dy, dz));
        }
        __syncthreads();  // skey reused next iteration
    }
}

// ---------------------------------------------------------------------------
// Kernel 2: KNN dist-vec at each anchor + gather + concat epilogue.
// One block per (object, anchor) = 2048 blocks.
// d2 row exactly as reference: sq_a + sq_j - 2*dot; self excluded; 16 rounds
// of block-min extraction (ties -> smallest index, matching top_k order) with
// accumulation in ascending-distance order (matching mean over top_k output).
// ---------------------------------------------------------------------------
__global__ __launch_bounds__(TPB) void knn_gather_kernel(
    const float* __restrict__ pos, const float* __restrict__ vel,
    const float* __restrict__ phys, const float* __restrict__ refp,
    const int* __restrict__ anchors, float* __restrict__ out) {
    const int bid = blockIdx.x;      // obj*AK + k
    const int obj = bid >> 6;
    const float* pts = pos + (size_t)obj * NPTS * 3;
    const int a = anchors[bid];
    const int t = threadIdx.x;

    const float ax = pts[a * 3 + 0];
    const float ay = pts[a * 3 + 1];
    const float az = pts[a * 3 + 2];
    const float sqa = sq3(ax, ay, az);

    __shared__ float sdist[NPTS];
    __shared__ unsigned long long skey[TPB];

    #pragma unroll
    for (int i = 0; i < PPT; i++) {
        const int j = t + i * TPB;
        const float x = pts[j * 3 + 0];
        const float y = pts[j * 3 + 1];
        const float z = pts[j * 3 + 2];
        const float sqj = sq3(x, y, z);
        const float dot =
            __fadd_rn(__fadd_rn(__fmul_rn(ax, x), __fmul_rn(ay, y)), __fmul_rn(az, z));
        float d2 = __fsub_rn(__fadd_rn(sqa, sqj), __fmul_rn(2.0f, dot));
        if (j == a) d2 = 1e30f;  // self-exclusion (reference adds 1e10*I)
        sdist[j] = d2;
    }
    __syncthreads();

    float sx = 0.0f, sy = 0.0f, sz = 0.0f;  // only thread 0's copy is used

    for (int r = 0; r < KNN; r++) {
        // sortable key: flip sign bit (or all bits if negative) so unsigned
        // compare == float compare even for tiny-negative d2 from rounding.
        unsigned long long best = ~0ull;
        #pragma unroll
        for (int i = 0; i < PPT; i++) {
            const int j = t + i * TPB;
            unsigned int b = __float_as_uint(sdist[j]);
            b ^= (b & 0x80000000u) ? 0xFFFFFFFFu : 0x80000000u;
            const unsigned long long key =
                ((unsigned long long)b << 32) | (unsigned int)j;
            if (key < best) best = key;
        }
        skey[t] = best;
        __syncthreads();
        for (int off = TPB / 2; off > 0; off >>= 1) {
            if (t < off) {
                if (skey[t + off] < skey[t]) skey[t] = skey[t + off];
            }
            __syncthreads();
        }
        const int idx = (int)((unsigned int)skey[0]);
        if (t == 0) {
            sx = __fadd_rn(sx, __fsub_rn(pts[idx * 3 + 0], ax));
            sy = __fadd_rn(sy, __fsub_rn(pts[idx * 3 + 1], ay));
            sz = __fadd_rn(sz, __fsub_rn(pts[idx * 3 + 2], az));
            sdist[idx] = 1e30f;  // remove from candidate set
        }
        __syncthreads();
    }

    if (t == 0) {
        float* o = out + (size_t)bid * 12;
        // mean offset to 16 nearest neighbors; /16 is exact as *0.0625
        o[0] = __fmul_rn(sx, 0.0625f);
        o[1] = __fmul_rn(sy, 0.0625f);
        o[2] = __fmul_rn(sz, 0.0625f);
        const size_t base = (size_t)obj * NPTS * 3 + (size_t)a * 3;
        o[3] = vel[base + 0];
        o[4] = vel[base + 1];
        o[5] = vel[base + 2];
        o[6] = __fsub_rn(pos[base + 0], refp[base + 0]);
        o[7] = __fsub_rn(pos[base + 1], refp[base + 1]);
        o[8] = __fsub_rn(pos[base + 2], refp[base + 2]);
        const float* ph = phys + (size_t)obj * 3;
        o[9]  = ph[0];
        o[10] = ph[1];
        o[11] = ph[2];
    }
}

extern "C" void kernel_launch(void* const* d_in, const int* in_sizes, int n_in,
                              void* d_out, int out_size, void* d_ws, size_t ws_size,
                              hipStream_t stream) {
    const float* pos  = (const float*)d_in[0];  // (4,8,2048,3)
    const float* vel  = (const float*)d_in[1];  // (4,8,2048,3)
    const float* phys = (const float*)d_in[2];  // (4,8,3)
    const float* refp = (const float*)d_in[3];  // (4,8,2048,3)
    float* out = (float*)d_out;                 // (4,8,64,12)

    const int n_obj = in_sizes[2] / 3;          // 32 objects
    int* anchors = (int*)d_ws;                  // n_obj * 64 ints

    fps_kernel<<<n_obj, TPB, 0, stream>>>(pos, anchors);
    knn_gather_kernel<<<n_obj * AK, TPB, 0, stream>>>(pos, vel, phys, refp,
                                                      anchors, out);
}

// Round 2
// 115.547 us; speedup vs baseline: 1.2823x; 1.2823x over previous
//
#include <hip/hip_runtime.h>
#include <stdint.h>

// Problem constants (fixed by setup_inputs: B=4, N_obj=8, N_v=2048)
#define NPTS 2048
#define KNN  16
#define AK   64
#define TPB  256
#define FPT  (NPTS / TPB)   // fps: 8 points per thread
#define KPL  (NPTS / 64)    // knn: 32 points per lane (one wave per anchor)

typedef unsigned long long u64;
typedef unsigned int u32;

// Exact float32 helpers (no FMA contraction -> match numpy reference bitwise)
__device__ __forceinline__ float sq3(float x, float y, float z) {
    return __fadd_rn(__fadd_rn(__fmul_rn(x, x), __fmul_rn(y, y)), __fmul_rn(z, z));
}

// ---------------------------------------------------------------------------
// Kernel 1: farthest-point sampling, one block (256 thr / 4 waves) per object.
// Per step: in-register per-thread argmax (slot tracking), 6-step shuffle
// butterfly on packed (float_bits<<32 | ~j) key, single cross-wave LDS merge
// with ONE double-buffered barrier per step. Coords broadcast from LDS stage.
// ---------------------------------------------------------------------------
__global__ __launch_bounds__(TPB) void fps_kernel(const float* __restrict__ pos,
                                                  int* __restrict__ anchors) {
    const int obj = blockIdx.x;
    const int t = threadIdx.x;
    __shared__ float sp[NPTS * 3];   // 24 KB staged point cloud
    __shared__ u64 skey[8];          // double-buffered cross-wave merge slots

    {   // stage: 6144 floats = 1536 float4, 6 per thread, coalesced
        const float4* g4 = (const float4*)(pos + (size_t)obj * NPTS * 3);
        float4* s4 = (float4*)sp;
        #pragma unroll
        for (int i = 0; i < 6; i++) s4[t + i * TPB] = g4[t + i * TPB];
    }
    __syncthreads();

    float px[FPT], py[FPT], pz[FPT], mind[FPT];
    {
        const float ax0 = sp[0], ay0 = sp[1], az0 = sp[2];
        #pragma unroll
        for (int i = 0; i < FPT; i++) {
            const int j = t + i * TPB;
            px[i] = sp[j * 3 + 0];
            py[i] = sp[j * 3 + 1];
            pz[i] = sp[j * 3 + 2];
            mind[i] = sq3(__fsub_rn(px[i], ax0), __fsub_rn(py[i], ay0),
                          __fsub_rn(pz[i], az0));
        }
    }
    if (t == 0) anchors[obj * AK + 0] = 0;

    for (int s = 1; s < AK; s++) {
        // per-thread argmax; strict-greater keeps earliest slot (smallest j)
        float bv = mind[0];
        u32 slot = 0;
        #pragma unroll
        for (int i = 1; i < FPT; i++)
            if (mind[i] > bv) { bv = mind[i]; slot = (u32)i; }
        // mind >= 0 so raw float bits are order-monotonic; ~j => smaller j
        // wins ties under max (matches jnp.argmax first-occurrence).
        const u32 j = (u32)t + slot * TPB;
        u64 key = ((u64)__float_as_uint(bv) << 32) | (u32)(~j);

        #pragma unroll
        for (int off = 32; off > 0; off >>= 1) {
            const u64 o = (u64)__shfl_xor((long long)key, off, 64);
            if (o > key) key = o;
        }

        u64* sk = &skey[(s & 1) * 4];
        if ((t & 63) == 0) sk[t >> 6] = key;
        __syncthreads();   // only barrier per step (skey double-buffered)

        u64 k = sk[0];
        if (sk[1] > k) k = sk[1];
        if (sk[2] > k) k = sk[2];
        if (sk[3] > k) k = sk[3];
        const int idx = (int)(~(u32)k);
        if (t == 0) anchors[obj * AK + s] = idx;

        const float bx = sp[idx * 3 + 0];   // uniform address -> broadcast
        const float by = sp[idx * 3 + 1];
        const float bz = sp[idx * 3 + 2];
        #pragma unroll
        for (int i = 0; i < FPT; i++) {
            const float d2 = sq3(__fsub_rn(px[i], bx), __fsub_rn(py[i], by),
                                 __fsub_rn(pz[i], bz));
            mind[i] = fminf(mind[i], d2);
        }
    }
}

// ---------------------------------------------------------------------------
// Kernel 2: KNN dist-vec + gather + concat. ONE WAVE per anchor, 4 anchors
// per block, zero barriers after the staging sync. Transformed distance bits
// live in 32 registers/lane; removal of the previous winner is folded into
// the next round's scan via index equality (persistent cndmask write).
// ---------------------------------------------------------------------------
__global__ __launch_bounds__(TPB) void knn_gather_kernel(
    const float* __restrict__ pos, const float* __restrict__ vel,
    const float* __restrict__ phys, const float* __restrict__ refp,
    const int* __restrict__ anchors, float* __restrict__ out) {
    const int t = threadIdx.x;
    const int wid = t >> 6, lane = t & 63;
    const int g = blockIdx.x * 4 + wid;   // global anchor id (obj*64 + k)
    const int obj = g >> 6;

    __shared__ float sp[NPTS * 3];   // 24 KB staged point cloud (one object)
    {
        const float4* g4 = (const float4*)(pos + (size_t)obj * NPTS * 3);
        float4* s4 = (float4*)sp;
        #pragma unroll
        for (int i = 0; i < 6; i++) s4[t + i * TPB] = g4[t + i * TPB];
    }
    const int a = anchors[g];   // global read, no LDS hazard
    __syncthreads();            // the only barrier

    const float ax = sp[a * 3 + 0], ay = sp[a * 3 + 1], az = sp[a * 3 + 2];
    const float sqa = sq3(ax, ay, az);

    // d2 row exactly as reference: (sq_a + sq_j) - 2*dot.
    // Stored as sign-flipped sortable u32 bits (handles tiny-negative d2).
    u32 b[KPL];
    #pragma unroll
    for (int i = 0; i < KPL; i++) {
        const int j = lane + i * 64;
        const float x = sp[j * 3 + 0], y = sp[j * 3 + 1], z = sp[j * 3 + 2];
        const float sqj = sq3(x, y, z);
        const float dot = __fadd_rn(
            __fadd_rn(__fmul_rn(ax, x), __fmul_rn(ay, y)), __fmul_rn(az, z));
        const float d2 = __fsub_rn(__fadd_rn(sqa, sqj), __fmul_rn(2.0f, dot));
        u32 bb = __float_as_uint(d2);
        bb ^= (bb & 0x80000000u) ? 0xFFFFFFFFu : 0x80000000u;
        b[i] = (j == a) ? 0xFFFFFFFFu : bb;   // self-exclusion
    }

    float sx = 0.0f, sy = 0.0f, sz = 0.0f;   // uniform, redundant on all lanes
    int winj = -1;                            // previous round's winner index

    for (int r = 0; r < KNN; r++) {
        const int wm = winj - lane;   // == i*64 only on the owning lane
        u32 bv = 0xFFFFFFFFu;
        u32 slot = 0;
        #pragma unroll
        for (int i = 0; i < KPL; i++) {
            if (wm == i * 64) b[i] = 0xFFFFFFFFu;  // persistent removal
            if (b[i] < bv) { bv = b[i]; slot = (u32)i; }  // strict: keeps min j
        }
        u64 key = ((u64)bv << 32) | (u32)(lane + slot * 64);
        #pragma unroll
        for (int off = 32; off > 0; off >>= 1) {
            const u64 o = (u64)__shfl_xor((long long)key, off, 64);
            if (o < key) key = o;   // ties -> smaller j (top_k stability)
        }
        winj = (int)(u32)key;

        // accumulate in ascending-distance order (== top_k output order)
        const float wx = sp[winj * 3 + 0];   // uniform -> LDS broadcast
        const float wy = sp[winj * 3 + 1];
        const float wz = sp[winj * 3 + 2];
        sx = __fadd_rn(sx, __fsub_rn(wx, ax));
        sy = __fadd_rn(sy, __fsub_rn(wy, ay));
        sz = __fadd_rn(sz, __fsub_rn(wz, az));
    }

    if (lane == 0) {
        float* o = out + (size_t)g * 12;
        o[0] = __fmul_rn(sx, 0.0625f);   // /16 exact as *2^-4
        o[1] = __fmul_rn(sy, 0.0625f);
        o[2] = __fmul_rn(sz, 0.0625f);
        const size_t base = (size_t)obj * NPTS * 3 + (size_t)a * 3;
        o[3] = vel[base + 0];
        o[4] = vel[base + 1];
        o[5] = vel[base + 2];
        o[6] = __fsub_rn(pos[base + 0], refp[base + 0]);
        o[7] = __fsub_rn(pos[base + 1], refp[base + 1]);
        o[8] = __fsub_rn(pos[base + 2], refp[base + 2]);
        const float* ph = phys + (size_t)obj * 3;
        o[9]  = ph[0];
        o[10] = ph[1];
        o[11] = ph[2];
    }
}

extern "C" void kernel_launch(void* const* d_in, const int* in_sizes, int n_in,
                              void* d_out, int out_size, void* d_ws, size_t ws_size,
                              hipStream_t stream) {
    const float* pos  = (const float*)d_in[0];  // (4,8,2048,3)
    const float* vel  = (const float*)d_in[1];  // (4,8,2048,3)
    const float* phys = (const float*)d_in[2];  // (4,8,3)
    const float* refp = (const float*)d_in[3];  // (4,8,2048,3)
    float* out = (float*)d_out;                 // (4,8,64,12)

    const int n_obj = in_sizes[2] / 3;          // 32 objects
    int* anchors = (int*)d_ws;                  // n_obj * 64 ints

    fps_kernel<<<n_obj, TPB, 0, stream>>>(pos, anchors);
    knn_gather_kernel<<<n_obj * AK / 4, TPB, 0, stream>>>(pos, vel, phys, refp,
                                                          anchors, out);
}

// Round 3
// 109.575 us; speedup vs baseline: 1.3522x; 1.0545x over previous
//
#include <hip/hip_runtime.h>
#include <stdint.h>

// Problem constants (fixed by setup_inputs: B=4, N_obj=8, N_v=2048)
#define NPTS 2048
#define KNN  16
#define AK   64
#define TPB  256
#define FPT  (NPTS / TPB)   // fps: 8 points per thread
#define KPL  (NPTS / 64)    // knn: 32 points per lane (one wave per anchor)

typedef unsigned long long u64;
typedef unsigned int u32;
#define UMAX 0xFFFFFFFFFFFFFFFFull

// Exact float32 helpers (no FMA contraction -> match numpy reference bitwise)
__device__ __forceinline__ float sq3(float x, float y, float z) {
    return __fadd_rn(__fadd_rn(__fmul_rn(x, x), __fmul_rn(y, y)), __fmul_rn(z, z));
}

// ---------------------------------------------------------------------------
// 64-lane butterfly reductions on u64 keys. Steps 1,2,4,8 use DPP
// permutations (VALU latency ~12cyc vs ds_bpermute ~45cyc); 16,32 use shfl.
// quad_perm(1,0,3,2)=0xB1 is xor1; quad_perm(2,3,0,1)=0x4E is xor2;
// row_half_mirror(0x141)=lane^7 acts as xor4 once quads are uniform;
// row_mirror(0x140)=lane^15 acts as xor8 once 8-groups are uniform.
// All are full permutations -> every lane reads a valid lane; all lanes end
// with the global result.
// ---------------------------------------------------------------------------
template <int CTRL>
__device__ __forceinline__ u64 dpp64(u64 k) {
    const int lo = __builtin_amdgcn_update_dpp((int)(u32)k, (int)(u32)k,
                                               CTRL, 0xF, 0xF, false);
    const int hi = __builtin_amdgcn_update_dpp((int)(u32)(k >> 32),
                                               (int)(u32)(k >> 32),
                                               CTRL, 0xF, 0xF, false);
    return ((u64)(u32)hi << 32) | (u32)lo;
}

__device__ __forceinline__ u64 wave_max64(u64 k) {
    u64 o;
    o = dpp64<0xB1>(k);  if (o > k) k = o;
    o = dpp64<0x4E>(k);  if (o > k) k = o;
    o = dpp64<0x141>(k); if (o > k) k = o;
    o = dpp64<0x140>(k); if (o > k) k = o;
    o = (u64)__shfl_xor((long long)k, 16, 64); if (o > k) k = o;
    o = (u64)__shfl_xor((long long)k, 32, 64); if (o > k) k = o;
    return k;
}

__device__ __forceinline__ u64 wave_min64(u64 k) {
    u64 o;
    o = dpp64<0xB1>(k);  if (o < k) k = o;
    o = dpp64<0x4E>(k);  if (o < k) k = o;
    o = dpp64<0x141>(k); if (o < k) k = o;
    o = dpp64<0x140>(k); if (o < k) k = o;
    o = (u64)__shfl_xor((long long)k, 16, 64); if (o < k) k = o;
    o = (u64)__shfl_xor((long long)k, 32, 64); if (o < k) k = o;
    return k;
}

// ---------------------------------------------------------------------------
// Kernel 1: farthest-point sampling, one block (4 waves) per object.
// Per step: fused min-update + argmax scan (regs), DPP/shfl butterfly,
// per-wave lane0 pre-fetches its wave-winner coords BEFORE the barrier so the
// post-barrier merge yields idx+coords in one LDS round-trip. One barrier
// per step (double-buffered exchange slots).
// ---------------------------------------------------------------------------
__global__ __launch_bounds__(TPB) void fps_kernel(const float* __restrict__ pos,
                                                  int* __restrict__ anchors) {
    const int obj = blockIdx.x;
    const int t = threadIdx.x;
    const int wid = t >> 6, lane = t & 63;

    __shared__ float sX[NPTS], sY[NPTS], sZ[NPTS];  // SoA: bank-perfect
    __shared__ u64 skey[8];      // double-buffered per-wave winner keys
    __shared__ float4 scrd[8];   // double-buffered per-wave winner coords

    const float* pts = pos + (size_t)obj * NPTS * 3;
    #pragma unroll
    for (int i = 0; i < FPT; i++) {
        const int j = t + i * TPB;
        sX[j] = pts[j * 3 + 0];
        sY[j] = pts[j * 3 + 1];
        sZ[j] = pts[j * 3 + 2];
    }
    __syncthreads();

    float px[FPT], py[FPT], pz[FPT], mind[FPT];
    u64 key;
    {
        const float ax0 = sX[0], ay0 = sY[0], az0 = sZ[0];
        float bv = -1.0f; u32 bj = 0;
        #pragma unroll
        for (int i = 0; i < FPT; i++) {
            const int j = t + i * TPB;
            px[i] = sX[j]; py[i] = sY[j]; pz[i] = sZ[j];
            const float d2 = sq3(__fsub_rn(px[i], ax0), __fsub_rn(py[i], ay0),
                                 __fsub_rn(pz[i], az0));
            mind[i] = d2;
            if (d2 > bv) { bv = d2; bj = (u32)j; }  // strict: smallest j kept
        }
        // mind >= 0 -> float bits order-monotonic; ~j -> smaller j wins ties
        key = ((u64)__float_as_uint(bv) << 32) | (u32)(~bj);
    }
    if (t == 0) anchors[obj * AK + 0] = 0;

    for (int s = 1; s < AK; s++) {
        const u64 wk = wave_max64(key);     // all lanes hold wave-winner
        const int side = (s & 1) * 4;
        if (lane == 0) {
            const int widx = (int)(~(u32)wk);
            skey[side + wid] = wk;
            scrd[side + wid] = make_float4(sX[widx], sY[widx], sZ[widx], 0.f);
        }
        __syncthreads();   // only barrier per step
        u64 ka = skey[side + 0];
        float4 ca = scrd[side + 0];
        { const u64 k1 = skey[side + 1]; const float4 q = scrd[side + 1];
          if (k1 > ka) { ka = k1; ca = q; } }
        { const u64 k2 = skey[side + 2]; const float4 q = scrd[side + 2];
          if (k2 > ka) { ka = k2; ca = q; } }
        { const u64 k3 = skey[side + 3]; const float4 q = scrd[side + 3];
          if (k3 > ka) { ka = k3; ca = q; } }
        if (t == 0) anchors[obj * AK + s] = (int)(~(u32)ka);
        if (s == AK - 1) break;   // no update needed after last anchor

        // fused min-update + argmax scan (exact: direct (p-b)^2 like lax.scan)
        float bv = -1.0f; u32 bj = 0;
        #pragma unroll
        for (int i = 0; i < FPT; i++) {
            const float d2 = sq3(__fsub_rn(px[i], ca.x), __fsub_rn(py[i], ca.y),
                                 __fsub_rn(pz[i], ca.z));
            const float nm = fminf(mind[i], d2);
            mind[i] = nm;
            if (nm > bv) { bv = nm; bj = (u32)(t + i * TPB); }
        }
        key = ((u64)__float_as_uint(bv) << 32) | (u32)(~bj);
    }
}

// ---------------------------------------------------------------------------
// Kernel 2: KNN dist-vec + gather + concat. ONE WAVE per anchor, 4 anchors
// per block. Keys k = (sortbits<<32)|j are unique -> single v_cmp_lt_u64
// folds. Per-lane sorted top-4 cache: per round just a butterfly min + O(1)
// pop on the winning lane; rare refill (lane contributed >4 of the global
// top-16) recomputes with threshold > thr — exact because winners leave in
// ascending key order, so "not yet taken" == "key > last taken key".
// ---------------------------------------------------------------------------
__global__ __launch_bounds__(TPB) void knn_gather_kernel(
    const float* __restrict__ pos, const float* __restrict__ vel,
    const float* __restrict__ phys, const float* __restrict__ refp,
    const int* __restrict__ anchors, float* __restrict__ out) {
    const int t = threadIdx.x;
    const int wid = t >> 6, lane = t & 63;
    const int g = blockIdx.x * 4 + wid;   // global anchor id (obj*64 + k)
    const int obj = g >> 6;

    __shared__ float sX[NPTS], sY[NPTS], sZ[NPTS];
    const float* pts = pos + (size_t)obj * NPTS * 3;
    #pragma unroll
    for (int i = 0; i < FPT; i++) {
        const int j = t + i * TPB;
        sX[j] = pts[j * 3 + 0];
        sY[j] = pts[j * 3 + 1];
        sZ[j] = pts[j * 3 + 2];
    }
    const int a = anchors[g];   // global read, no LDS hazard
    __syncthreads();            // the only barrier

    const float ax = sX[a], ay = sY[a], az = sZ[a];
    const float sqa = sq3(ax, ay, az);

    // d2 row exactly as reference: (sq_a + sq_j) - 2*dot, sign-flip sortable.
    u64 k[KPL];
    #pragma unroll
    for (int i = 0; i < KPL; i++) {
        const int j = lane + i * 64;
        const float x = sX[j], y = sY[j], z = sZ[j];
        const float sqj = sq3(x, y, z);
        const float dot = __fadd_rn(
            __fadd_rn(__fmul_rn(ax, x), __fmul_rn(ay, y)), __fmul_rn(az, z));
        const float d2 = __fsub_rn(__fadd_rn(sqa, sqj), __fmul_rn(2.0f, dot));
        u32 bb = __float_as_uint(d2);
        bb ^= (bb & 0x80000000u) ? 0xFFFFFFFFu : 0x80000000u;
        k[i] = (j == a) ? UMAX : (((u64)bb << 32) | (u32)j);
    }

    // per-lane 4 smallest, ascending: c0 < c1 < c2 < c3 (keys unique)
    u64 c0 = UMAX, c1 = UMAX, c2 = UMAX, c3 = UMAX;
    #pragma unroll
    for (int i = 0; i < KPL; i++) c0 = (k[i] < c0) ? k[i] : c0;
    #pragma unroll
    for (int i = 0; i < KPL; i++) {
        const u64 v = (k[i] > c0) ? k[i] : UMAX; c1 = (v < c1) ? v : c1;
    }
    #pragma unroll
    for (int i = 0; i < KPL; i++) {
        const u64 v = (k[i] > c1) ? k[i] : UMAX; c2 = (v < c2) ? v : c2;
    }
    #pragma unroll
    for (int i = 0; i < KPL; i++) {
        const u64 v = (k[i] > c2) ? k[i] : UMAX; c3 = (v < c3) ? v : c3;
    }

    float accx = 0.f, accy = 0.f, accz = 0.f;
    u64 thr = 0;
    for (int r = 0; r < KNN; r++) {
        if (c0 == UMAX) {   // rare refill: 4 smallest keys > thr
            #pragma unroll
            for (int i = 0; i < KPL; i++) {
                const u64 v = (k[i] > thr) ? k[i] : UMAX; c0 = (v < c0) ? v : c0;
            }
            #pragma unroll
            for (int i = 0; i < KPL; i++) {
                const u64 v = (k[i] > c0) ? k[i] : UMAX; c1 = (v < c1) ? v : c1;
            }
            #pragma unroll
            for (int i = 0; i < KPL; i++) {
                const u64 v = (k[i] > c1) ? k[i] : UMAX; c2 = (v < c2) ? v : c2;
            }
            #pragma unroll
            for (int i = 0; i < KPL; i++) {
                const u64 v = (k[i] > c2) ? k[i] : UMAX; c3 = (v < c3) ? v : c3;
            }
        }
        const u64 w = wave_min64(c0);       // global min; ties impossible
        const int winj = (int)(u32)w;
        // accumulate in ascending-distance order (== top_k output order)
        const float wx = sX[winj], wy = sY[winj], wz = sZ[winj];  // broadcast
        accx = __fadd_rn(accx, __fsub_rn(wx, ax));
        accy = __fadd_rn(accy, __fsub_rn(wy, ay));
        accz = __fadd_rn(accz, __fsub_rn(wz, az));
        if (c0 == w) {                       // exactly one lane pops
            thr = c0; c0 = c1; c1 = c2; c2 = c3; c3 = UMAX;
        }
    }

    if (lane == 0) {
        float* o = out + (size_t)g * 12;
        o[0] = __fmul_rn(accx, 0.0625f);   // /16 exact as *2^-4
        o[1] = __fmul_rn(accy, 0.0625f);
        o[2] = __fmul_rn(accz, 0.0625f);
        const size_t base = (size_t)obj * NPTS * 3 + (size_t)a * 3;
        o[3] = vel[base + 0];
        o[4] = vel[base + 1];
        o[5] = vel[base + 2];
        o[6] = __fsub_rn(pos[base + 0], refp[base + 0]);
        o[7] = __fsub_rn(pos[base + 1], refp[base + 1]);
        o[8] = __fsub_rn(pos[base + 2], refp[base + 2]);
        const float* ph = phys + (size_t)obj * 3;
        o[9]  = ph[0];
        o[10] = ph[1];
        o[11] = ph[2];
    }
}

extern "C" void kernel_launch(void* const* d_in, const int* in_sizes, int n_in,
                              void* d_out, int out_size, void* d_ws, size_t ws_size,
                              hipStream_t stream) {
    const float* pos  = (const float*)d_in[0];  // (4,8,2048,3)
    const float* vel  = (const float*)d_in[1];  // (4,8,2048,3)
    const float* phys = (const float*)d_in[2];  // (4,8,3)
    const float* refp = (const float*)d_in[3];  // (4,8,2048,3)
    float* out = (float*)d_out;                 // (4,8,64,12)

    const int n_obj = in_sizes[2] / 3;          // 32 objects
    int* anchors = (int*)d_ws;                  // n_obj * 64 ints

    fps_kernel<<<n_obj, TPB, 0, stream>>>(pos, anchors);
    knn_gather_kernel<<<n_obj * AK / 4, TPB, 0, stream>>>(pos, vel, phys, refp,
                                                          anchors, out);
}